// Round 12
// baseline (95.332 us; speedup 1.0000x reference)
//
#include <hip/hip_runtime.h>

// DIAGNOSTIC ROUND: R10 structure exactly, inner loop amplified x8 so the
// kernel surfaces in rocprof top-5 (poison fills ~39us were masking it).
// Idempotent: each rep re-zeroes accumulators; last rep's values are used.
// asm sinks keep dead reps live; opaque zoff blocks load hoisting across reps.

#define BATCH    2
#define NPART    4096
#define NTHREADS 512
#define IBLK     16                   // i per block
#define ILANES   8                    // lane slots in i-dim (2 i packed per lane)
#define JCH      (NTHREADS / ILANES)  // 64 j-chunks per block
#define JLEN     (NPART / JCH)        // 64 j per chunk
#define NIB      (NPART / IBLK)       // 256 i-blocks per batch
#define REPS     8                    // diagnostic amplification factor

typedef float v2f __attribute__((ext_vector_type(2)));

__global__ __launch_bounds__(NTHREADS, 4) void lj_fused_diag(
        const float* __restrict__ q, const float* __restrict__ p,
        const float* __restrict__ m, float* __restrict__ dq,
        float* __restrict__ dp) {
    __shared__ float red[JCH * 6 * ILANES];   // 12 KB

    const int ib = blockIdx.x;
    const int b  = blockIdx.y;
    const int t  = threadIdx.x;
    const int il = t & (ILANES - 1);
    const int jc = t >> 3;                    // 0..63

    const float* qb = q + (size_t)b * NPART * 3;

    const int i0 = ib * IBLK + il;            // first i of this lane
    const int i1 = i0 + ILANES;               // second i of this lane
    const v2f qx = {qb[i0 * 3 + 0], qb[i1 * 3 + 0]};
    const v2f qy = {qb[i0 * 3 + 1], qb[i1 * 3 + 1]};
    const v2f qz = {qb[i0 * 3 + 2], qb[i1 * 3 + 2]};

    const float4* jq4 = (const float4*)(qb + (size_t)jc * JLEN * 3);

    v2f fx, fy, fz;

    #pragma unroll 1
    for (int rep = 0; rep < REPS; ++rep) {
        // Opaque zero: compiler must treat each rep's loads as fresh
        int zoff;
        asm volatile("v_mov_b32 %0, 0" : "=v"(zoff));
        const float4* jr = jq4 + zoff;

        fx = (v2f)0.0f; fy = (v2f)0.0f; fz = (v2f)0.0f;

        #pragma unroll 2
        for (int it = 0; it < JLEN / 4; ++it) {
            const float4 A = jr[3 * it + 0];   // x0 y0 z0 x1
            const float4 B = jr[3 * it + 1];   // y1 z1 x2 y2
            const float4 C = jr[3 * it + 2];   // z2 x3 y3 z3
            const float jxs[4] = {A.x, A.w, B.z, C.y};
            const float jys[4] = {A.y, B.x, B.w, C.z};
            const float jzs[4] = {A.z, B.y, C.x, C.w};
            #pragma unroll
            for (int u = 0; u < 4; ++u) {
                const v2f dx = qx - (v2f)jxs[u];
                const v2f dy = qy - (v2f)jys[u];
                const v2f dz = qz - (v2f)jzs[u];
                v2f r2 = dx * dx;
                r2 = __builtin_elementwise_fma(dy, dy, r2);
                r2 = __builtin_elementwise_fma(dz, dz, r2);
                // r2 == 0.0f exactly <=> i == j (reference's mask semantics)
                v2f inv;
                inv.x = (r2.x > 0.0f) ? __builtin_amdgcn_rcpf(r2.x) : 0.0f;
                inv.y = (r2.y > 0.0f) ? __builtin_amdgcn_rcpf(r2.y) : 0.0f;
                const v2f inv2 = inv * inv;
                const v2f s6 = inv2 * inv;                                 // sigma=1
                const v2f c1 = __builtin_elementwise_fma((v2f)48.0f, s6, (v2f)(-24.0f));
                const v2f coeff = (inv * s6) * c1;   // 24*inv*s6*(2*s6-1)
                fx = __builtin_elementwise_fma(coeff, dx, fx);
                fy = __builtin_elementwise_fma(coeff, dy, fy);
                fz = __builtin_elementwise_fma(coeff, dz, fz);
            }
        }

        if (rep != REPS - 1) {
            // keep this rep's results live without storing them
            asm volatile("" :: "v"(fx.x), "v"(fx.y), "v"(fy.x),
                              "v"(fy.y), "v"(fz.x), "v"(fz.y));
        }
    }

    // Stash this thread's 6 partials (2 i-halves x 3 components)
    red[(jc * 6 + 0) * ILANES + il] = fx.x;
    red[(jc * 6 + 1) * ILANES + il] = fx.y;
    red[(jc * 6 + 2) * ILANES + il] = fy.x;
    red[(jc * 6 + 3) * ILANES + il] = fy.y;
    red[(jc * 6 + 4) * ILANES + il] = fz.x;
    red[(jc * 6 + 5) * ILANES + il] = fz.y;
    __syncthreads();

    // 48 threads: one per (c, i-in-block). Sum 64 chunk partials, store dp;
    // fuse dq = p/m for the same (i, c).
    if (t < 48) {
        const int c   = t >> 4;        // 0..2
        const int ii  = t & 15;        // 0..15
        const int h   = ii >> 3;       // which packed half
        const int il2 = ii & 7;
        const int slot = c * 2 + h;
        float s = 0.0f;
        #pragma unroll
        for (int k = 0; k < JCH; ++k) {
            s += red[(k * 6 + slot) * ILANES + il2];
        }
        const size_t gi = (size_t)b * NPART + ib * IBLK + ii;
        dp[gi * 3 + c] = s;
        dq[gi * 3 + c] = p[gi * 3 + c] / m[gi];   // exact IEEE div, tiny count
    }
}

extern "C" void kernel_launch(void* const* d_in, const int* in_sizes, int n_in,
                              void* d_out, int out_size, void* d_ws, size_t ws_size,
                              hipStream_t stream) {
    const float* q = (const float*)d_in[0];
    const float* p = (const float*)d_in[1];
    const float* m = (const float*)d_in[2];
    // d_in[3] = t, unused by the reference outputs

    const int n_elem = BATCH * NPART * 3;   // 24576 per output tensor
    float* dq_out = (float*)d_out;          // first output: dq
    float* dp_out = (float*)d_out + n_elem; // second output: dp

    dim3 grid(NIB, BATCH);                  // 512 blocks x 512 threads
    lj_fused_diag<<<grid, NTHREADS, 0, stream>>>(q, p, m, dq_out, dp_out);
}

// Round 13
// 17.519 us; speedup vs baseline: 5.4416x; 5.4416x over previous
//
#include <hip/hip_runtime.h>

// Problem constants (match reference setup_inputs)
#define BATCH    2
#define NPART    4096
#define NTHREADS 512
#define IBLK     8                    // i per block
#define ILANES   4                    // lane slots in i-dim (2 i packed per lane)
#define JCH      (NTHREADS / ILANES)  // 128 j-chunks per block
#define JLEN     (NPART / JCH)        // 32 j per chunk
#define NIB      (NPART / IBLK)       // 512 i-blocks per batch

typedef float v2f __attribute__((ext_vector_type(2)));

// One (j, 2-i) interaction; v2f packs the two i's. MASKED handles i==j (r2==0).
template <bool MASKED>
__device__ inline void lj_body(float jx, float jy, float jz,
                               v2f qx, v2f qy, v2f qz,
                               v2f& fx, v2f& fy, v2f& fz) {
    const v2f dx = qx - (v2f)jx;
    const v2f dy = qy - (v2f)jy;
    const v2f dz = qz - (v2f)jz;
    v2f r2 = dx * dx;
    r2 = __builtin_elementwise_fma(dy, dy, r2);
    r2 = __builtin_elementwise_fma(dz, dz, r2);
    v2f inv;
    if (MASKED) {   // r2==0.0f exactly <=> i==j (reference's mask semantics)
        inv.x = (r2.x > 0.0f) ? __builtin_amdgcn_rcpf(r2.x) : 0.0f;
        inv.y = (r2.y > 0.0f) ? __builtin_amdgcn_rcpf(r2.y) : 0.0f;
    } else {
        inv.x = __builtin_amdgcn_rcpf(r2.x);
        inv.y = __builtin_amdgcn_rcpf(r2.y);
    }
    const v2f inv2 = inv * inv;
    const v2f s6 = inv2 * inv;                                      // sigma = 1
    const v2f c1 = __builtin_elementwise_fma((v2f)48.0f, s6, (v2f)(-24.0f));
    const v2f coeff = (inv * s6) * c1;     // 24*inv*s6*(2*s6-1)
    fx = __builtin_elementwise_fma(coeff, dx, fx);
    fy = __builtin_elementwise_fma(coeff, dy, fy);
    fz = __builtin_elementwise_fma(coeff, dz, fz);
}

template <bool MASKED>
__device__ inline void chunk_loop(const float4* __restrict__ jq4,
                                  v2f qx, v2f qy, v2f qz,
                                  v2f& fx, v2f& fy, v2f& fz) {
    #pragma unroll
    for (int it = 0; it < JLEN / 4; ++it) {
        const float4 A = jq4[3 * it + 0];   // x0 y0 z0 x1
        const float4 B = jq4[3 * it + 1];   // y1 z1 x2 y2
        const float4 C = jq4[3 * it + 2];   // z2 x3 y3 z3
        lj_body<MASKED>(A.x, A.y, A.z, qx, qy, qz, fx, fy, fz);
        lj_body<MASKED>(A.w, B.x, B.y, qx, qy, qz, fx, fy, fz);
        lj_body<MASKED>(B.z, B.w, C.x, qx, qy, qz, fx, fy, fz);
        lj_body<MASKED>(C.y, C.z, C.w, qx, qy, qz, fx, fy, fz);
    }
}

// Fully fused single dispatch. Block owns 8 i's x all 4096 j (128 chunks of 32
// across lanes); LDS reduction. 1024 blocks x 512 thr -> 4 blocks/CU (100% occ).
// Only wave (ib>>6) can contain the diagonal -> 7/8 waves run maskless bodies.
__global__ __launch_bounds__(NTHREADS, 8) void lj_fused(
        const float* __restrict__ q, const float* __restrict__ p,
        const float* __restrict__ m, float* __restrict__ dq,
        float* __restrict__ dp) {
    __shared__ float red[JCH * 6 * ILANES];   // 12 KB
    __shared__ float red2[24 * 8];            // stage-1 partials

    const int ib = blockIdx.x;
    const int b  = blockIdx.y;
    const int t  = threadIdx.x;
    const int il = t & (ILANES - 1);
    const int jc = t >> 2;                    // 0..127

    const float* qb = q + (size_t)b * NPART * 3;

    const int i0 = ib * IBLK + il;            // first i of this lane
    const int i1 = i0 + ILANES;               // second i of this lane
    const v2f qx = {qb[i0 * 3 + 0], qb[i1 * 3 + 0]};
    const v2f qy = {qb[i0 * 3 + 1], qb[i1 * 3 + 1]};
    const v2f qz = {qb[i0 * 3 + 2], qb[i1 * 3 + 2]};

    v2f fx = (v2f)0.0f, fy = (v2f)0.0f, fz = (v2f)0.0f;

    const float4* jq4 = (const float4*)(qb + (size_t)jc * JLEN * 3);

    // Block's 8 i's all live in j-chunk (ib>>2) -> only wave (ib>>6) masked.
    if ((t >> 6) == (ib >> 6)) {
        chunk_loop<true >(jq4, qx, qy, qz, fx, fy, fz);
    } else {
        chunk_loop<false>(jq4, qx, qy, qz, fx, fy, fz);
    }

    // Stash 6 partials (2 i-halves x 3 comps): slot = c*2+h
    red[(jc * 6 + 0) * ILANES + il] = fx.x;
    red[(jc * 6 + 1) * ILANES + il] = fx.y;
    red[(jc * 6 + 2) * ILANES + il] = fy.x;
    red[(jc * 6 + 3) * ILANES + il] = fy.y;
    red[(jc * 6 + 4) * ILANES + il] = fz.x;
    red[(jc * 6 + 5) * ILANES + il] = fz.y;
    __syncthreads();

    // Stage 1: 192 threads, each sums 16 of the 128 chunk partials.
    if (t < 192) {
        const int sl = t >> 3;         // 0..23: slot*4 + il
        const int g  = t & 7;          // 0..7: group of 16 chunks
        const int slot = sl >> 2;
        const int il2  = sl & 3;
        float s = 0.0f;
        #pragma unroll
        for (int qq = 0; qq < 16; ++qq) {
            s += red[((g * 16 + qq) * 6 + slot) * ILANES + il2];
        }
        red2[sl * 8 + g] = s;
    }
    __syncthreads();

    // Stage 2: 24 threads -> one (c, i-in-block) each; fuse dq = p/m.
    if (t < 24) {
        float s = 0.0f;
        #pragma unroll
        for (int g = 0; g < 8; ++g) s += red2[t * 8 + g];
        const int slot = t >> 2;       // c*2 + h
        const int il2  = t & 3;
        const int c  = slot >> 1;
        const int h  = slot & 1;
        const int ii = h * ILANES + il2;
        const size_t gi = (size_t)b * NPART + ib * IBLK + ii;
        dp[gi * 3 + c] = s;
        dq[gi * 3 + c] = p[gi * 3 + c] / m[gi];   // exact IEEE div, tiny count
    }
}

extern "C" void kernel_launch(void* const* d_in, const int* in_sizes, int n_in,
                              void* d_out, int out_size, void* d_ws, size_t ws_size,
                              hipStream_t stream) {
    const float* q = (const float*)d_in[0];
    const float* p = (const float*)d_in[1];
    const float* m = (const float*)d_in[2];
    // d_in[3] = t, unused by the reference outputs

    const int n_elem = BATCH * NPART * 3;   // 24576 per output tensor
    float* dq_out = (float*)d_out;          // first output: dq
    float* dp_out = (float*)d_out + n_elem; // second output: dp

    dim3 grid(NIB, BATCH);                  // 1024 blocks x 512 threads
    lj_fused<<<grid, NTHREADS, 0, stream>>>(q, p, m, dq_out, dp_out);
}